// Round 8
// baseline (555721.094 us; speedup 1.0000x reference)
//
#include <hip/hip_runtime.h>
#include <hip/hip_bf16.h>
#include <stdint.h>

#define TT 1024
#define DD 512
#define HH 512

typedef short bf16x8 __attribute__((ext_vector_type(8)));
typedef float f32x4 __attribute__((ext_vector_type(4)));
typedef unsigned long long u64;
typedef unsigned int u32;
typedef unsigned short u16;

// ---- workspace layout (bytes) ----
#define OFF_WPACK 0ull
#define SZ_WPACK  (32ull*4*4*8*1024)          // 4 MiB B-fragments
#define OFF_XS    (OFF_WPACK + SZ_WPACK)       // 64 MiB x A-frag blobs
#define SZ_XS     (1024ull*8*2*8*512)
#define OFF_HBL   (OFF_XS + SZ_XS)             // local (XCD-L2) tagged h: [g8][buf4][2048 u64]
#define SZ_HB1    (8ull*4*2048*8)
#define OFF_HBM   (OFF_HBL + SZ_HB1)           // mirror (MALL) tagged h, same layout
#define OFF_TEST  (OFF_HBM + SZ_HB1)           // 256 u64 coherence-test words
#define OFF_RDV   (OFF_TEST + 2048ull)         // 256 u32 rendezvous flags
#define OFF_VERD  (OFF_RDV + 1024ull)          // 256 u32 verdicts

__device__ __forceinline__ u16 f2bf(float f){
  u32 u = __builtin_bit_cast(u32, f);
  u32 r = (u + 0x7fffu + ((u >> 16) & 1u)) >> 16;   // RNE
  return (u16)r;
}

// ---- clear all cross-wg state every launch (no cross-replay state) ----
__global__ void k_clear(u64* hbl, u64* hbm, u64* test, u32* rdv, u32* verd){
  int id = blockIdx.x * 256 + threadIdx.x;          // 65536
  hbl[id] = 0x8000000000000000ull;
  hbm[id] = 0x8000000000000000ull;
  if (id < 256){ test[id] = 0; rdv[id] = 0; verd[id] = 0; }
}

// ---- pack Wcat=[Wx;Wh] into B-frags (verified r5-r7) ----
__global__ void k_pack_w(const float* __restrict__ Wx, const float* __restrict__ Wh,
                         u16* __restrict__ wp){
  int id = blockIdx.x * 256 + threadIdx.x;          // 262144
  int lane = id & 63;
  int kk = (id >> 6) & 7, G = (id >> 9) & 3, q = (id >> 11) & 3, p = id >> 13;
  int col = G * 512 + p * 16 + (lane & 15);
  int kb  = q * 256 + kk * 32 + (lane >> 4) * 8;
  union { u16 v[8]; uint4 u; } pk;
#pragma unroll
  for (int j = 0; j < 8; ++j){
    int k = kb + j;
    float f = (k < 512) ? Wx[k * 2048 + col] : Wh[(k - 512) * 2048 + col];
    pk.v[j] = f2bf(f);
  }
  long long fid = ((p * 4 + q) * 4 + G) * 8 + kk;
  *((uint4*)wp + fid * 64 + lane) = pk.u;
}

// ---- x -> per-(t, g<8, q<2, kk<8) 8-row half-frag blobs (512 B each) ----
__global__ void k_conv_x(const float* __restrict__ x, unsigned char* __restrict__ xs){
  int id = blockIdx.x * 256 + threadIdx.x;          // 4,194,304
  int ksub = id & 3, row = (id >> 2) & 7, kk = (id >> 5) & 7;
  int q = (id >> 8) & 1, g = (id >> 9) & 7, t = id >> 12;
  int k = q * 256 + kk * 32 + ksub * 8;
  const float* src = x + ((long long)(g * 8 + row) * TT + t) * DD + k;
  union { u16 v[8]; uint4 u; } pk;
#pragma unroll
  for (int j = 0; j < 8; ++j) pk.v[j] = f2bf(src[j]);
  size_t dst = ((((size_t)t * 8 + g) * 2 + q) * 8 + kk) * 512 + (size_t)(ksub * 128 + row * 16);
  *(uint4*)(xs + dst) = pk.u;
}

// ---- h0 -> tagged words, buf 3, tag 0xFFFFFFFF, BOTH buffers ----
__global__ void k_conv_h0(const float* __restrict__ h0, u64* __restrict__ hbl,
                          u64* __restrict__ hbm){
  int id = blockIdx.x * 256 + threadIdx.x;          // 16384
  int row = id & 7, c = (id >> 3) & 255, g = id >> 11;
  u32 v0 = f2bf(h0[(g * 8 + row) * HH + 2 * c]);
  u32 v1 = f2bf(h0[(g * 8 + row) * HH + 2 * c + 1]);
  u64 wd = (0xFFFFFFFFull << 32) | ((u64)v1 << 16) | v0;
  size_t idx = ((size_t)g * 4 + 3) * 2048 + c * 8 + row;
  hbl[idx] = wd;
  hbm[idx] = wd;
}

#define LD(I, B, OFF) asm volatile("global_load_dwordx2 %0, %1, off offset:" OFF " sc0" \
                                   : "=v"(wv[I]) : "v"(B))
#define LD32(B0, B1) do { \
  LD(0,B0,"0");    LD(1,B0,"64");   LD(2,B0,"128");  LD(3,B0,"192");   \
  LD(4,B0,"1024"); LD(5,B0,"1088"); LD(6,B0,"1152"); LD(7,B0,"1216");  \
  LD(8,B0,"2048"); LD(9,B0,"2112"); LD(10,B0,"2176");LD(11,B0,"2240"); \
  LD(12,B0,"3072");LD(13,B0,"3136");LD(14,B0,"3200");LD(15,B0,"3264"); \
  LD(16,B1,"0");    LD(17,B1,"64");   LD(18,B1,"128");  LD(19,B1,"192");   \
  LD(20,B1,"1024"); LD(21,B1,"1088"); LD(22,B1,"1152"); LD(23,B1,"1216");  \
  LD(24,B1,"2048"); LD(25,B1,"2112"); LD(26,B1,"2176"); LD(27,B1,"2240");  \
  LD(28,B1,"3072"); LD(29,B1,"3136"); LD(30,B1,"3200"); LD(31,B1,"3264");  \
  asm volatile("s_waitcnt vmcnt(0)" ::: "memory"); } while(0)

// ---- persistent scan: 256 wgs (8 groups x 32) x 256 threads ----
// Startup: behavioral coherence test decides per-group fast (XCD-L2 exchange)
// vs slow (MALL agent-scope, r5-proven). Producers always dual-publish
// (local plain store + mirror agent store); fast consumers poll local with a
// bounded round count and fall back to the mirror -> no deadlock possible.
__launch_bounds__(256, 1)
__global__ void k_lstm(const float* __restrict__ bias_g, float* __restrict__ out,
                       const u16* __restrict__ wp, const unsigned char* __restrict__ xs,
                       u64* __restrict__ hbl, u64* __restrict__ hbm,
                       u64* __restrict__ test, u32* __restrict__ rdv,
                       u32* __restrict__ verd)
{
  __shared__ float part[2][4096];   // [buf][q*1024 + G*256 + row*16 + col]
  __shared__ int sfast;

  const int tid  = threadIdx.x;
  const int lane = tid & 63;
  const int q    = tid >> 6;
  const int b    = blockIdx.x;
  const int g    = b & 7;
  const int p    = b >> 3;
  const int khi  = lane >> 4;
  const int llo  = lane & 15;

  // ---- behavioral coherence test (startup only) ----
  if (tid == 0){
    u64* tw = test + g * 32 + p;
    u64 pat = (0xC0DEull << 48) | (u64)b;
    asm volatile("global_store_dwordx2 %0, %1, off" :: "v"(tw), "v"(pat) : "memory");
    asm volatile("s_waitcnt vmcnt(0)" ::: "memory");
    __hip_atomic_store(rdv + b, 1u, __ATOMIC_RELAXED, __HIP_MEMORY_SCOPE_AGENT);
  }
  if (tid < 64){
    u32 v;
    do {
      v = (lane < 32) ? __hip_atomic_load(rdv + g + 8 * lane, __ATOMIC_RELAXED,
                                          __HIP_MEMORY_SCOPE_AGENT) : 1u;
    } while (!__all(v != 0));
    bool ok = false;
    const u64 expv = (0xC0DEull << 48) | (u64)(g + 8 * lane);
    const u64* tp = test + g * 32 + lane;
    for (int it = 0; it < 4096 && !ok; ++it){
      u64 tv = expv;
      if (lane < 32){
        asm volatile("global_load_dwordx2 %0, %1, off sc0" : "=v"(tv) : "v"(tp));
        asm volatile("s_waitcnt vmcnt(0)" ::: "memory");
      }
      ok = __all(tv == expv);
    }
    if (lane == 0)
      __hip_atomic_store(verd + b, ok ? 1u : 2u, __ATOMIC_RELAXED, __HIP_MEMORY_SCOPE_AGENT);
    u32 vv;
    do {
      vv = (lane < 32) ? __hip_atomic_load(verd + g + 8 * lane, __ATOMIC_RELAXED,
                                           __HIP_MEMORY_SCOPE_AGENT) : 1u;
    } while (!__all(vv != 0));
    bool af = __all(vv == 1u);
    if (lane == 0) sfast = af ? 1 : 0;
  }
  __syncthreads();
  const bool fast = (sfast != 0);

  // persistent B fragments: 128 VGPRs
  bf16x8 bfrag[4][8];
  {
    const bf16x8* wpf = (const bf16x8*)wp;
#pragma unroll
    for (int G = 0; G < 4; ++G)
#pragma unroll
      for (int kk = 0; kk < 8; ++kk)
        bfrag[G][kk] = wpf[(((p * 4 + q) * 4 + G) * 8 + kk) * 64 + lane];
  }

  // gate mapping (x-waves, tid<128): 8 rows x 16 cols
  const int row_g = tid >> 4;
  const int col_g = tid & 15;
  float bia[4];
#pragma unroll
  for (int G = 0; G < 4; ++G) bia[G] = bias_g[G * 512 + p * 16 + col_g];
  float cs = 0.f;

  u64* lbase = hbl + (size_t)g * 4 * 2048;
  u64* mbase = hbm + (size_t)g * 4 * 2048;
  const int kq = q & 1;
  const int cw = kq * 1024 + khi * 32 + (lane & 7);          // consumer word base
  const int swidx = (p * 8 + (col_g >> 1)) * 8 + row_g;      // producer word idx
  const bool storer = ((col_g & 1) == 0);
  float* outp = out + ((size_t)(g * 8 + row_g) * TT) * HH + p * 16 + col_g;

  const bool is_h = (q >= 2);

  for (int t = 0; t < TT; ++t){
    f32x4 acc[4];
#pragma unroll
    for (int n = 0; n < 4; ++n) acc[n] = (f32x4){0.f, 0.f, 0.f, 0.f};

    if (!is_h){
      // x K-half: plain cached frag loads (rows duplicated via &7 addressing)
      const unsigned char* xb = xs + ((((size_t)t * 8 + g) * 2 + q) * 8) * 512
                              + (size_t)(khi * 128 + (lane & 7) * 16);
#pragma unroll
      for (int kk = 0; kk < 8; ++kk){
        bf16x8 av = *(const bf16x8*)(xb + kk * 512);
#pragma unroll
        for (int n = 0; n < 4; ++n)
          acc[n] = __builtin_amdgcn_mfma_f32_16x16x32_bf16(av, bfrag[n][kk], acc[n], 0, 0, 0);
      }
    } else {
      // h K-half: poll tagged words of h(t-1)
      const u32 tg = (u32)(t - 1);
      u64 wv[32];
      bool got = false;
      if (fast){
        const u64* b0 = lbase + (size_t)((t + 3) & 3) * 2048 + cw;
        const u64* b1 = b0 + 512;
        int rounds = 0;
        for (;;){
          LD32(b0, b1);
          bool ok = true;
#pragma unroll
          for (int j = 0; j < 32; ++j) ok &= ((u32)(wv[j] >> 32) == tg);
          if (__all(ok)){ got = true; break; }
          if (++rounds >= 1024) break;     // bounded: fall back to mirror
        }
      }
      if (!got){
        const u64* m0 = mbase + (size_t)((t + 3) & 3) * 2048 + cw;
        for (;;){
#pragma unroll
          for (int j = 0; j < 32; ++j){
            int kk = j >> 2, jj = j & 3;
            wv[j] = __hip_atomic_load(m0 + kk * 128 + jj * 8,
                                      __ATOMIC_RELAXED, __HIP_MEMORY_SCOPE_AGENT);
          }
          bool ok = true;
#pragma unroll
          for (int j = 0; j < 32; ++j) ok &= ((u32)(wv[j] >> 32) == tg);
          if (__all(ok)) break;
          __builtin_amdgcn_s_sleep(1);
        }
      }
      asm volatile("" ::: "memory");
#pragma unroll
      for (int kk = 0; kk < 8; ++kk){
        union { u32 d[4]; bf16x8 v; } af;
#pragma unroll
        for (int jj = 0; jj < 4; ++jj) af.d[jj] = (u32)wv[kk * 4 + jj];
#pragma unroll
        for (int n = 0; n < 4; ++n)
          acc[n] = __builtin_amdgcn_mfma_f32_16x16x32_bf16(af.v, bfrag[n][kk], acc[n], 0, 0, 0);
      }
    }

    // K-partials to double-buffered LDS
    float* pb = &part[t & 1][0];
#pragma unroll
    for (int n = 0; n < 4; ++n)
#pragma unroll
      for (int r = 0; r < 4; ++r)
        pb[q * 1024 + n * 256 + (khi * 4 + r) * 16 + llo] = acc[n][r];
    __syncthreads();   // single barrier per step

    // gates on x-waves (tid<128); h-waves loop straight back to polling
    if (tid < 128){
      const float* pr = pb + row_g * 16 + col_g;
      float aG[4];
#pragma unroll
      for (int G = 0; G < 4; ++G)
        aG[G] = pr[G * 256] + pr[1024 + G * 256] + pr[2048 + G * 256]
              + pr[3072 + G * 256] + bia[G];
      float gi = 1.f / (1.f + __expf(-aG[0]));
      float gf = 1.f / (1.f + __expf(-aG[1]));
      float go = 1.f / (1.f + __expf(-aG[2]));
      float e2 = __expf(-2.f * fabsf(aG[3]));
      float gg = __builtin_copysignf((1.f - e2) / (1.f + e2), aG[3]);
      float c  = gf * cs + gi * gg;
      cs = c;
      float ec = __expf(-2.f * fabsf(c));
      float th = __builtin_copysignf((1.f - ec) / (1.f + ec), c);
      float h  = go * th;

      u32 hb16 = f2bf(h);
      u32 pv   = __shfl_down(hb16, 1);
      if (storer){
        u64 hword = ((u64)(u32)t << 32) | ((u64)pv << 16) | hb16;
        size_t off = (size_t)(t & 3) * 2048 + swidx;
        if (fast){
          u64* lp = lbase + off;
          asm volatile("global_store_dwordx2 %0, %1, off" :: "v"(lp), "v"(hword) : "memory");
        }
        __hip_atomic_store(mbase + off, hword, __ATOMIC_RELAXED, __HIP_MEMORY_SCOPE_AGENT);
      }
      outp[(size_t)t * HH] = h;
    }
  }
}

extern "C" void kernel_launch(void* const* d_in, const int* in_sizes, int n_in,
                              void* d_out, int out_size, void* d_ws, size_t ws_size,
                              hipStream_t stream){
  const float* x  = (const float*)d_in[0];
  const float* h0 = (const float*)d_in[1];
  const float* Wx = (const float*)d_in[2];
  const float* Wh = (const float*)d_in[3];
  const float* b  = (const float*)d_in[4];
  float* out = (float*)d_out;

  unsigned char* ws = (unsigned char*)d_ws;
  u16*  wp   = (u16*)(ws + OFF_WPACK);
  unsigned char* xs = ws + OFF_XS;
  u64*  hbl  = (u64*)(ws + OFF_HBL);
  u64*  hbm  = (u64*)(ws + OFF_HBM);
  u64*  test = (u64*)(ws + OFF_TEST);
  u32*  rdv  = (u32*)(ws + OFF_RDV);
  u32*  verd = (u32*)(ws + OFF_VERD);

  hipLaunchKernelGGL(k_clear,   dim3(256),   dim3(256), 0, stream, hbl, hbm, test, rdv, verd);
  hipLaunchKernelGGL(k_pack_w,  dim3(1024),  dim3(256), 0, stream, Wx, Wh, wp);
  hipLaunchKernelGGL(k_conv_x,  dim3(16384), dim3(256), 0, stream, x, xs);
  hipLaunchKernelGGL(k_conv_h0, dim3(64),    dim3(256), 0, stream, h0, hbl, hbm);
  hipLaunchKernelGGL(k_lstm,    dim3(256),   dim3(256), 0, stream, b, out, wp, xs, hbl, hbm,
                     test, rdv, verd);
}

// Round 10
// 6611.183 us; speedup vs baseline: 84.0577x; 84.0577x over previous
//
#include <hip/hip_runtime.h>
#include <hip/hip_bf16.h>
#include <stdint.h>

#define TT 1024
#define DD 512
#define HH 512

typedef short bf16x8 __attribute__((ext_vector_type(8)));
typedef float f32x4 __attribute__((ext_vector_type(4)));
typedef unsigned long long u64;
typedef unsigned int u32;
typedef unsigned short u16;

// ---- workspace layout (bytes) ----
#define OFF_WPACK 0ull
#define SZ_WPACK  (4096ull*1024)           // 4 MiB: 4096 B-frags x 1 KiB (r9 bug: was 2 MiB)
#define OFF_XS    (OFF_WPACK + SZ_WPACK)    // 64 MiB: x A-frag blobs per (t,g,kk)
#define SZ_XS     (1024ull*8*16*512)
#define OFF_HB    (OFF_XS + SZ_XS)          // [g 8][buf 4][2048 u64] tagged h = 512 KiB
#define SZ_HB     (8ull*4*2048*8)

__device__ __forceinline__ u16 f2bf(float f){
  u32 u = __builtin_bit_cast(u32, f);
  u32 r = (u + 0x7fffu + ((u >> 16) & 1u)) >> 16;   // RNE
  return (u16)r;
}

// ---- clear hbuf tags every launch (no cross-replay state) ----
__global__ void k_clear(u64* hb){
  int id = blockIdx.x * 256 + threadIdx.x;          // 65536
  hb[id] = 0x8000000000000000ull;                   // tag matches no (u32)(t-1)
}

// ---- pack Wcat=[Wx;Wh] B-frags: wave (p,q) cols n=G*4+c -> col G*512+p*16+q*4+c,
//      frag kk: lane holds B[k=kk*32+(lane>>4)*8+j][n=lane&15] ----
__global__ void k_pack_w(const float* __restrict__ Wx, const float* __restrict__ Wh,
                         u16* __restrict__ wp){
  int id = blockIdx.x * 256 + threadIdx.x;          // 262144
  int lane = id & 63;
  int kk = (id >> 6) & 31, q = (id >> 11) & 3, p = id >> 13;
  int n = lane & 15, G = n >> 2, cc = n & 3;
  int col = G * 512 + p * 16 + q * 4 + cc;
  int kb  = kk * 32 + (lane >> 4) * 8;
  union { u16 v[8]; uint4 u; } pk;
#pragma unroll
  for (int j = 0; j < 8; ++j){
    int k = kb + j;
    float f = (k < 512) ? Wx[k * 2048 + col] : Wh[(k - 512) * 2048 + col];
    pk.v[j] = f2bf(f);
  }
  long long fid = (p * 4 + q) * 32 + kk;
  *((uint4*)wp + fid * 64 + lane) = pk.u;
}

// ---- x -> per-(t,g,kk<16) 8-row A-frag blobs (512 B each) ----
// consumer lane reads slot = (lane>>4)*8 + (lane&7)
__global__ void k_conv_x(const float* __restrict__ x, unsigned char* __restrict__ xs){
  int id = blockIdx.x * 256 + threadIdx.x;          // 4,194,304
  int slot = id & 31, kk = (id >> 5) & 15, g = (id >> 9) & 7, t = id >> 12;
  int row = slot & 7, khi = slot >> 3;
  const float* src = x + ((long long)(g * 8 + row) * TT + t) * DD + kk * 32 + khi * 8;
  union { u16 v[8]; uint4 u; } pk;
#pragma unroll
  for (int j = 0; j < 8; ++j) pk.v[j] = f2bf(src[j]);
  *(uint4*)(xs + ((size_t)(t * 8 + g) * 16 + kk) * 512 + slot * 16) = pk.u;
}

// ---- h0 -> tagged words (cpair, row), buf 3, tag 0xFFFFFFFF ----
__global__ void k_conv_h0(const float* __restrict__ h0, u64* __restrict__ hb){
  int id = blockIdx.x * 256 + threadIdx.x;          // 16384
  int row = id & 7, cp = (id >> 3) & 255, g = id >> 11;
  u32 v0 = f2bf(h0[(g * 8 + row) * HH + 2 * cp]);
  u32 v1 = f2bf(h0[(g * 8 + row) * HH + 2 * cp + 1]);
  hb[((size_t)g * 4 + 3) * 2048 + cp * 8 + row] =
      (0xFFFFFFFFull << 32) | ((u64)v1 << 16) | v0;
}

// ---- persistent scan: 256 wgs x 4 waves; each wave fully autonomous ----
// wave (g=b&7, p=b>>3, q): 8 batch rows (dup to M=16), cols p*16+q*4..+4,
// full K=1024 in one accumulator (x kk 0-15, h kk 16-31). No __syncthreads
// in the loop. Exchange: tagged u64 words via MALL (r5-proven primitive).
__launch_bounds__(256, 1)
__global__ void k_lstm(const float* __restrict__ bias_g, float* __restrict__ out,
                       const u16* __restrict__ wp, const unsigned char* __restrict__ xs,
                       u64* __restrict__ hb)
{
  __shared__ float xch[4][128];      // per-wave [n16][row8] gate transpose

  const int tid  = threadIdx.x;
  const int lane = tid & 63;
  const int q    = tid >> 6;
  const int b    = blockIdx.x;
  const int g    = b & 7;
  const int p    = b >> 3;
  const int khi  = lane >> 4;
  const int n    = lane & 15;
  const int row8 = lane & 7;

  // persistent B fragments: 32 frags = 128 VGPRs
  bf16x8 bfrag[32];
  {
    const bf16x8* wpf = (const bf16x8*)wp;
#pragma unroll
    for (int kk = 0; kk < 32; ++kk)
      bfrag[kk] = wpf[(size_t)((p * 4 + q) * 32 + kk) * 64 + lane];
  }

  // canonical gate lane (lane<32): output (row r, col cb+c)
  const int r  = (lane >> 2) & 7;
  const int c  = lane & 3;
  const int cb = p * 16 + q * 4;
  float bia[4];
#pragma unroll
  for (int G = 0; G < 4; ++G) bia[G] = bias_g[G * 512 + cb + c];
  float cs = 0.f;

  u64* gb = hb + (size_t)g * 4 * 2048;
  const int lofs  = khi * 32 + row8;                       // consumer addr part
  const int swidx = (p * 8 + q * 2 + (c >> 1)) * 8 + r;    // producer word idx
  float* outp = out + ((size_t)(g * 8 + r) * TT) * HH + cb + c;

  const unsigned char* xg = xs + (size_t)g * 16 * 512;
  const int xoff = (khi * 8 + row8) * 16;

  // x-frag prefetch registers (64 VGPRs)
  uint4 xf[16];
  {
    const unsigned char* xb = xg + xoff;                   // t = 0
#pragma unroll
    for (int kk = 0; kk < 16; ++kk) xf[kk] = *(const uint4*)(xb + kk * 512);
  }

  for (int t = 0; t < TT; ++t){
    f32x4 acc = (f32x4){0.f, 0.f, 0.f, 0.f};
    // x half (prefetched; overlaps producers' publish of h(t-1))
#pragma unroll
    for (int kk = 0; kk < 16; ++kk)
      acc = __builtin_amdgcn_mfma_f32_16x16x32_bf16(
                __builtin_bit_cast(bf16x8, xf[kk]), bfrag[kk], acc, 0, 0, 0);

    // poll tagged h(t-1): 64 words, non-divergent reload-all
    const u64* bb = gb + (size_t)((t + 3) & 3) * 2048;
    const u32 tg = (u32)(t - 1);
    u64 wv[64];
    for (;;){
#pragma unroll
      for (int khh = 0; khh < 16; ++khh)
#pragma unroll
        for (int u = 0; u < 4; ++u)
          wv[khh * 4 + u] = __hip_atomic_load(bb + khh * 128 + u * 8 + lofs,
                              __ATOMIC_RELAXED, __HIP_MEMORY_SCOPE_AGENT);
      bool ok = true;
#pragma unroll
      for (int j = 0; j < 64; ++j) ok &= ((u32)(wv[j] >> 32) == tg);
      if (__all(ok)) break;
    }
    asm volatile("" ::: "memory");

    // h half
#pragma unroll
    for (int khh = 0; khh < 16; ++khh){
      union { u32 d[4]; bf16x8 v; } af;
#pragma unroll
      for (int u = 0; u < 4; ++u) af.d[u] = (u32)wv[khh * 4 + u];
      acc = __builtin_amdgcn_mfma_f32_16x16x32_bf16(af.v, bfrag[16 + khh], acc, 0, 0, 0);
    }

    // prefetch next step's x (before stores so their wait stays counted)
    if (t + 1 < TT){
      const unsigned char* xb = xg + (size_t)(t + 1) * 8 * 16 * 512 + xoff;
#pragma unroll
      for (int kk = 0; kk < 16; ++kk) xf[kk] = *(const uint4*)(xb + kk * 512);
    }

    // wave-local gate transpose (rows 0..7; khi>=2 hold duplicated rows)
    if (khi < 2){
#pragma unroll
      for (int j = 0; j < 4; ++j)
        xch[q][n * 8 + khi * 4 + j] = acc[j];
    }
    asm volatile("s_waitcnt lgkmcnt(0)" ::: "memory");
    __builtin_amdgcn_sched_barrier(0);

    if (lane < 32){
      float aG[4];
#pragma unroll
      for (int G = 0; G < 4; ++G) aG[G] = xch[q][(G * 4 + c) * 8 + r] + bia[G];
      float gi = 1.f / (1.f + __expf(-aG[0]));
      float gf = 1.f / (1.f + __expf(-aG[1]));
      float go = 1.f / (1.f + __expf(-aG[2]));
      float e2 = __expf(-2.f * fabsf(aG[3]));
      float gg = __builtin_copysignf((1.f - e2) / (1.f + e2), aG[3]);
      float cn = gf * cs + gi * gg;
      cs = cn;
      float ec = __expf(-2.f * fabsf(cn));
      float th = __builtin_copysignf((1.f - ec) / (1.f + ec), cn);
      float h  = go * th;

      // publish first (critical path): tagged word = (t, h_{c+1}, h_c)
      u32 h16 = f2bf(h);
      u32 pv  = __shfl_down(h16, 1);
      if ((lane & 1) == 0){
        u64 word = ((u64)(u32)t << 32) | ((u64)(pv & 0xffffu) << 16) | (u64)(h16 & 0xffffu);
        __hip_atomic_store(gb + (size_t)(t & 3) * 2048 + swidx, word,
                           __ATOMIC_RELAXED, __HIP_MEMORY_SCOPE_AGENT);
      }
      outp[(size_t)t * HH] = h;
    }
  }
}

extern "C" void kernel_launch(void* const* d_in, const int* in_sizes, int n_in,
                              void* d_out, int out_size, void* d_ws, size_t ws_size,
                              hipStream_t stream){
  const float* x  = (const float*)d_in[0];
  const float* h0 = (const float*)d_in[1];
  const float* Wx = (const float*)d_in[2];
  const float* Wh = (const float*)d_in[3];
  const float* b  = (const float*)d_in[4];
  float* out = (float*)d_out;

  unsigned char* ws = (unsigned char*)d_ws;
  u16* wp = (u16*)(ws + OFF_WPACK);
  unsigned char* xs = ws + OFF_XS;
  u64* hb = (u64*)(ws + OFF_HB);

  hipLaunchKernelGGL(k_clear,   dim3(256),   dim3(256), 0, stream, hb);
  hipLaunchKernelGGL(k_pack_w,  dim3(1024),  dim3(256), 0, stream, Wx, Wh, wp);
  hipLaunchKernelGGL(k_conv_x,  dim3(16384), dim3(256), 0, stream, x, xs);
  hipLaunchKernelGGL(k_conv_h0, dim3(64),    dim3(256), 0, stream, h0, hb);
  hipLaunchKernelGGL(k_lstm,    dim3(256),   dim3(256), 0, stream, b, out, wp, xs, hb);
}

// Round 11
// 3007.831 us; speedup vs baseline: 184.7581x; 2.1980x over previous
//
#include <hip/hip_runtime.h>
#include <hip/hip_bf16.h>
#include <stdint.h>

#define TT 1024
#define DD 512
#define HH 512

typedef short bf16x8 __attribute__((ext_vector_type(8)));
typedef float f32x4 __attribute__((ext_vector_type(4)));
typedef unsigned long long u64;
typedef unsigned int u32;
typedef unsigned short u16;

// ---- workspace layout (bytes) ---- (identical to r5)
#define OFF_WPACK 0ull
#define SZ_WPACK  (32ull*4*4*8*1024)
#define OFF_XS    (OFF_WPACK + SZ_WPACK)
#define SZ_XS     (1024ull*4*2*8*1024)
#define OFF_HB    (OFF_XS + SZ_XS)
#define SZ_HB     (4ull*4*4096*8)

__device__ __forceinline__ u16 f2bf(float f){
  u32 u = __builtin_bit_cast(u32, f);
  u32 r = (u + 0x7fffu + ((u >> 16) & 1u)) >> 16;   // RNE
  return (u16)r;
}

// ---- clear all hbuf tags every launch (no cross-replay state) ----
__global__ void k_clear(u64* hb){
  int id = blockIdx.x * 256 + threadIdx.x;          // 65536
  hb[id] = 0x8000000000000000ull;
}

// ---- pack Wcat=[Wx;Wh] into B-frags (verified r5) ----
__global__ void k_pack_w(const float* __restrict__ Wx, const float* __restrict__ Wh,
                         u16* __restrict__ wp){
  int id = blockIdx.x * 256 + threadIdx.x;          // 262144
  int lane = id & 63;
  int kk = (id >> 6) & 7, G = (id >> 9) & 3, q = (id >> 11) & 3, p = id >> 13;
  int col = G * 512 + p * 16 + (lane & 15);
  int kb  = q * 256 + kk * 32 + (lane >> 4) * 8;
  union { u16 v[8]; uint4 u; } pk;
#pragma unroll
  for (int j = 0; j < 8; ++j){
    int k = kb + j;
    float f = (k < 512) ? Wx[k * 2048 + col] : Wh[(k - 512) * 2048 + col];
    pk.v[j] = f2bf(f);
  }
  long long fid = ((p * 4 + q) * 4 + G) * 8 + kk;
  *((uint4*)wp + fid * 64 + lane) = pk.u;
}

// ---- x -> per-(t,g,q,kk) M=16 A-frag blob (verified r5) ----
__global__ void k_conv_x(const float* __restrict__ x, uint4* __restrict__ xs){
  int id = blockIdx.x * 256 + threadIdx.x;          // 4,194,304
  int lane = id & 63, kk = (id >> 6) & 7, q = (id >> 9) & 1, g = (id >> 10) & 3, t = id >> 12;
  int row = g * 16 + (lane & 15);
  int k   = q * 256 + kk * 32 + (lane >> 4) * 8;
  const float* src = x + ((long long)row * TT + t) * DD + k;
  union { u16 v[8]; uint4 u; } pk;
#pragma unroll
  for (int j = 0; j < 8; ++j) pk.v[j] = f2bf(src[j]);
  xs[id] = pk.u;
}

// ---- h0 -> tagged words, buf 3, tag 0xFFFFFFFF (verified r5) ----
__global__ void k_conv_h0(const float* __restrict__ h0, u64* __restrict__ hb){
  int id = blockIdx.x * 256 + threadIdx.x;          // 16384
  int row = id & 15, cp = (id >> 4) & 255, g = id >> 12;
  u32 v0 = f2bf(h0[(g * 16 + row) * HH + 2 * cp]);
  u32 v1 = f2bf(h0[(g * 16 + row) * HH + 2 * cp + 1]);
  hb[((size_t)g * 4 + 3) * 4096 + cp * 16 + row] =
      (0xFFFFFFFFull << 32) | ((u64)v1 << 16) | v0;
}

// ---- persistent scan: 128 wgs (4 groups x 32) x 256 threads ----
// r11 = r5 with gates+publish moved to the x-waves (tid<128): h-waves return
// to polling immediately after the barrier; each x-thread computes 2 adjacent
// h-cols, builds its tagged u64 directly, stores output as float2.
// Poll / LDS-combine / buffers byte-identical to verified r5.
__launch_bounds__(256, 1)
__global__ void k_lstm(const float* __restrict__ bias_g, float* __restrict__ out,
                       const u16* __restrict__ wp, const uint4* __restrict__ xs,
                       u64* __restrict__ hbufs)
{
  __shared__ float part[2][4096];    // [buf][q*1024 + G*256 + row*16 + col]

  const int tid  = threadIdx.x;
  const int lane = tid & 63;
  const int q    = tid >> 6;
  const int w    = blockIdx.x;
  const int g    = w >> 5;
  const int p    = w & 31;
  const int khi  = lane >> 4;
  const int llo  = lane & 15;

  // persistent B fragments: 32 frags = 128 VGPRs
  bf16x8 bfrag[4][8];
  {
    const bf16x8* wpf = (const bf16x8*)wp;
#pragma unroll
    for (int G = 0; G < 4; ++G)
#pragma unroll
      for (int kk = 0; kk < 8; ++kk)
        bfrag[G][kk] = wpf[(((p * 4 + q) * 4 + G) * 8 + kk) * 64 + lane];
  }

  // gate mapping (x-waves, tid<128): thread -> (row r, col pair 2cp,2cp+1)
  const int tt = tid & 127;
  const int r  = tt >> 3;            // 0..15
  const int cp = tt & 7;             // 0..7
  float bia[4][2];
#pragma unroll
  for (int G = 0; G < 4; ++G)
#pragma unroll
    for (int e = 0; e < 2; ++e)
      bia[G][e] = bias_g[G * 512 + p * 16 + 2 * cp + e];
  float cs[2] = {0.f, 0.f};

  u64* gb = hbufs + (size_t)g * 4 * 4096;
  const int wbase = (((q & 1) * 128 + khi * 4) * 16) + llo;   // consumer (r5)
  const int swidx = (p * 8 + cp) * 16 + r;                    // producer word idx
  float* outp = out + ((size_t)(g * 16 + r) * TT) * HH + p * 16 + 2 * cp;

  const bool is_h = (q >= 2);

  for (int t = 0; t < TT; ++t){
    f32x4 acc[4];
#pragma unroll
    for (int n = 0; n < 4; ++n) acc[n] = (f32x4){0.f, 0.f, 0.f, 0.f};

    if (!is_h){
      // x K-half: plain cached frag loads, never blocks on recurrence
      const uint4* xb = xs + ((((size_t)t * 4 + g) * 2 + q) * 8) * 64 + lane;
#pragma unroll
      for (int kk = 0; kk < 8; ++kk){
        bf16x8 av = __builtin_bit_cast(bf16x8, xb[kk * 64]);
#pragma unroll
        for (int n = 0; n < 4; ++n)
          acc[n] = __builtin_amdgcn_mfma_f32_16x16x32_bf16(av, bfrag[n][kk], acc[n], 0, 0, 0);
      }
    } else {
      // h K-half: non-divergent reload-all poll of tagged h(t-1)  (r5 verbatim)
      const u64* bb = gb + (size_t)((t + 3) & 3) * 4096;
      const u32 tg = (u32)(t - 1);
      u64 wv[32];
      for (;;){
#pragma unroll
        for (int j = 0; j < 32; ++j){
          int kk = j >> 2, jj = j & 3;
          wv[j] = __hip_atomic_load(bb + wbase + kk * 256 + jj * 16,
                                    __ATOMIC_RELAXED, __HIP_MEMORY_SCOPE_AGENT);
        }
        bool ok = true;
#pragma unroll
        for (int j = 0; j < 32; ++j) ok &= ((u32)(wv[j] >> 32) == tg);
        if (__all(ok)) break;
      }
      asm volatile("" ::: "memory");
#pragma unroll
      for (int kk = 0; kk < 8; ++kk){
        union { u32 d[4]; bf16x8 v; } af;
#pragma unroll
        for (int jj = 0; jj < 4; ++jj) af.d[jj] = (u32)wv[kk * 4 + jj];
#pragma unroll
        for (int n = 0; n < 4; ++n)
          acc[n] = __builtin_amdgcn_mfma_f32_16x16x32_bf16(af.v, bfrag[n][kk], acc[n], 0, 0, 0);
      }
    }

    // K-partials to double-buffered LDS (r5 verbatim)
    float* pb = &part[t & 1][0];
#pragma unroll
    for (int n = 0; n < 4; ++n)
#pragma unroll
      for (int rr = 0; rr < 4; ++rr)
        pb[q * 1024 + n * 256 + (khi * 4 + rr) * 16 + llo] = acc[n][rr];
    __syncthreads();   // single barrier per step

    // gates + publish on x-waves only; h-waves loop straight back to polling
    if (tid < 128){
      const float* pr = pb + r * 16 + 2 * cp;
      float hv[2]; u32 hb16[2];
#pragma unroll
      for (int e = 0; e < 2; ++e){
        float aG[4];
#pragma unroll
        for (int G = 0; G < 4; ++G)
          aG[G] = pr[G * 256 + e] + pr[1024 + G * 256 + e]
                + pr[2048 + G * 256 + e] + pr[3072 + G * 256 + e] + bia[G][e];
        float gi = 1.f / (1.f + __expf(-aG[0]));
        float gf = 1.f / (1.f + __expf(-aG[1]));
        float go = 1.f / (1.f + __expf(-aG[2]));
        float e2 = __expf(-2.f * fabsf(aG[3]));
        float gg = __builtin_copysignf((1.f - e2) / (1.f + e2), aG[3]);
        float c  = gf * cs[e] + gi * gg;
        cs[e] = c;
        float ec = __expf(-2.f * fabsf(c));
        float th = __builtin_copysignf((1.f - ec) / (1.f + ec), c);
        hv[e] = go * th;
        hb16[e] = f2bf(hv[e]);
      }
      // publish first (critical path): tagged word = (t, h_{2cp+1}, h_{2cp})
      u64 word = ((u64)(u32)t << 32) | ((u64)hb16[1] << 16) | (u64)hb16[0];
      __hip_atomic_store(gb + (size_t)(t & 3) * 4096 + swidx, word,
                         __ATOMIC_RELAXED, __HIP_MEMORY_SCOPE_AGENT);
      // output off the critical path
      *(float2*)(outp + (size_t)t * HH) = make_float2(hv[0], hv[1]);
    }
  }
}

extern "C" void kernel_launch(void* const* d_in, const int* in_sizes, int n_in,
                              void* d_out, int out_size, void* d_ws, size_t ws_size,
                              hipStream_t stream){
  const float* x  = (const float*)d_in[0];
  const float* h0 = (const float*)d_in[1];
  const float* Wx = (const float*)d_in[2];
  const float* Wh = (const float*)d_in[3];
  const float* b  = (const float*)d_in[4];
  float* out = (float*)d_out;

  unsigned char* ws = (unsigned char*)d_ws;
  u16*   wp = (u16*)(ws + OFF_WPACK);
  uint4* xs = (uint4*)(ws + OFF_XS);
  u64*   hb = (u64*)(ws + OFF_HB);

  hipLaunchKernelGGL(k_clear,   dim3(256),   dim3(256), 0, stream, hb);
  hipLaunchKernelGGL(k_pack_w,  dim3(1024),  dim3(256), 0, stream, Wx, Wh, wp);
  hipLaunchKernelGGL(k_conv_x,  dim3(16384), dim3(256), 0, stream, x, xs);
  hipLaunchKernelGGL(k_conv_h0, dim3(64),    dim3(256), 0, stream, h0, hb);
  hipLaunchKernelGGL(k_lstm,    dim3(128),   dim3(256), 0, stream, b, out, wp, xs, hb);
}